// Round 1
// 150.538 us; speedup vs baseline: 1.0387x; 1.0387x over previous
//
#include <hip/hip_runtime.h>
#include <math.h>

// FFTConvReservoir: y = tanh(ifft(fft(u)*fft(K)).real + D*u); B=8,H=256,L=8192 fp32.
// Round 9: occupancy attack. Both kernels were latency-bound (VALUBusy 53%, HBM 25%,
// conflicts 0, Occupancy 17.7%): 64KB LDS caps 2 blocks/CU, and 256-thread blocks
// give only 2 waves/SIMD (conv) / 1 wave/SIMD (kfft). NT 256->512: 8-wave blocks,
// 16 elem/thread, pass A = dif_apply<4> (strides 4096..512), middle = 16 chunks of
// 512, 2 chunks/wave, wave-private in 3 levels (strides 256..64 / 32..8 / 4..1
// merged with *kw + inverse). Barriers stay 2. New unified swizzle SW(e) is exactly
// 2-way (free) for all patterns: stride-512 scatter, stride-64, 8-block, contig-8.
// __launch_bounds__(NT,4) pins VGPR<=128 so 2 blocks/CU (16 waves/CU) holds.
// Lessons kept: no b64 LDS (R7), no single-kernel fusion (R4), kw=(FFT(K)+D)/N
// folded in kfft (R6), scalar b32 LDS (R3). R5's launch-bounds lesson was the
// NT=256 regime (would force <=64 VGPR); at NT=512 the cap is 128.

#define LL 8192
#define NT 512
#define HH 256
#define TWO_PI 6.2831853071795864f
#define CP8  0.92387953251129f   // cos(pi/8)
#define SP8  0.38268343236509f   // sin(pi/8)
#define CP4  0.70710678118654752f // cos(pi/4) = sin(pi/4)
#define SP4  0.70710678118654752f

// Swizzle: XOR bits [8:6] into [2:0] and bits [7:6] into [4:3] (triangular ->
// bijective). All four access patterns are exactly 2-way (free on CDNA4):
//  A/A': e = m<<9 | tid            (wave varies bits [5:0] only)
//  M1:   e = c<<9 | j<<6 | lane    (wave varies bits [5:0] only)
//  M2:   e = c<<9 | b<<6 | j<<3 | r  -> bank gets b XORed in
//  M3:   e = c<<9 | lane<<3 | j      -> bank gets lane[5:3] (and [4:3]) XORed in
__device__ __forceinline__ int SW(int e) {
    return e ^ ((e >> 3) & 0x18) ^ ((e >> 6) & 7);
}
__device__ __forceinline__ float fast_tanh(float x) {
    float e = __expf(2.0f * x);
    return 1.0f - 2.0f / (e + 1.0f);
}

// Twiddle pyramid: level j at offset (1<<j)-1, length 2^j; top level chained cmul,
// lower levels by squaring. Level j entry m = exp(i*2^(JT-j)*(ang0 + m*angE)).
template<int JT>
__device__ __forceinline__ void fill_pyr_cs(float c0, float s0, float Er, float Ei,
                                            float* twr, float* twi) {
    const int off = (1 << JT) - 1;
    twr[off] = c0; twi[off] = s0;
    #pragma unroll
    for (int m = 1; m < (1 << JT); ++m) {
        const float pr = twr[off + m - 1], pi = twi[off + m - 1];
        twr[off + m] = pr * Er - pi * Ei;
        twi[off + m] = pr * Ei + pi * Er;
    }
    #pragma unroll
    for (int j = JT - 1; j >= 0; --j) {
        #pragma unroll
        for (int m = 0; m < (1 << j); ++m) {
            const float a = twr[(2 << j) - 1 + m], b = twi[(2 << j) - 1 + m];
            twr[(1 << j) - 1 + m] = a * a - b * b;
            twi[(1 << j) - 1 + m] = 2.0f * a * b;
        }
    }
}
template<int JT>
__device__ __forceinline__ void fill_pyr(float ang0, float Er, float Ei,
                                         float* twr, float* twi) {
    float s, c;
    __sincosf(ang0, &s, &c);
    fill_pyr_cs<JT>(c, s, Er, Ei, twr, twi);
}

template<int R2>
__device__ __forceinline__ void dif_apply(float* xr, float* xi,
                                          const float* twr, const float* twi) {
    #pragma unroll
    for (int j = R2 - 1; j >= 0; --j) {
        #pragma unroll
        for (int q = 0; q < (1 << (R2 - 1)); ++q) {
            const int mm = q & ((1 << j) - 1);
            const int m0 = ((q >> j) << (j + 1)) | mm;
            const int m1 = m0 + (1 << j);
            const float wr = twr[(1 << j) - 1 + mm], wi = twi[(1 << j) - 1 + mm];
            const float ar = xr[m0], ai = xi[m0], br = xr[m1], bi = xi[m1];
            xr[m0] = ar + br; xi[m0] = ai + bi;
            const float dr = ar - br, di = ai - bi;
            xr[m1] = dr * wr - di * wi;
            xi[m1] = dr * wi + di * wr;
        }
    }
}
template<int R2>
__device__ __forceinline__ void dit_apply(float* xr, float* xi,
                                          const float* twr, const float* twi) {
    #pragma unroll
    for (int j = 0; j < R2; ++j) {
        #pragma unroll
        for (int q = 0; q < (1 << (R2 - 1)); ++q) {
            const int mm = q & ((1 << j) - 1);
            const int m0 = ((q >> j) << (j + 1)) | mm;
            const int m1 = m0 + (1 << j);
            const float wr = twr[(1 << j) - 1 + mm], wi = twi[(1 << j) - 1 + mm];
            const float br = xr[m1] * wr - xi[m1] * wi;
            const float bi = xr[m1] * wi + xi[m1] * wr;
            const float ar = xr[m0], ai = xi[m0];
            xr[m0] = ar + br; xi[m0] = ai + bi;
            xr[m1] = ar - br; xi[m1] = ai - bi;
        }
    }
}

// Fwd pass A (stages of span 4096..512): 16 elements per thread at stride 512.
// After this, chunk m = contiguous [512m, 512m+512), local offset = tid.
__device__ __forceinline__ void fwd_A(float* xr, float* xi, int tid,
                                      float* re, float* im) {
    float twr[15], twi[15];
    fill_pyr<3>(-(TWO_PI / 8192.0f) * (float)tid, CP8, -SP8, twr, twi);
    dif_apply<4>(xr, xi, twr, twi);
    #pragma unroll
    for (int m = 0; m < 16; ++m) {
        const int p = SW(tid + (m << 9));
        re[p] = xr[m]; im[p] = xi[m];
    }
}

// M1: spans 256/128/64 within a 512-chunk. Lane = column, elements lane + 64j.
template<bool INV>
__device__ __forceinline__ void mid_M1(float* re, float* im, int lane, int wv) {
    float twr[7], twi[7];
    const float sgn = INV ? 1.0f : -1.0f;
    fill_pyr<2>(sgn * (TWO_PI / 512.0f) * (float)lane, CP4, sgn * SP4, twr, twi);
    #pragma unroll
    for (int r = 0; r < 2; ++r) {
        const int base = (((wv << 1) | r) << 9) + lane;
        float ar[8], ai[8];
        #pragma unroll
        for (int j = 0; j < 8; ++j) {
            const int p = SW(base + (j << 6));
            ar[j] = re[p]; ai[j] = im[p];
        }
        if (INV) dit_apply<3>(ar, ai, twr, twi);
        else     dif_apply<3>(ar, ai, twr, twi);
        #pragma unroll
        for (int j = 0; j < 8; ++j) {
            const int p = SW(base + (j << 6));
            re[p] = ar[j]; im[p] = ai[j];
        }
    }
}

// M2: spans 32/16/8 within each 64-block. Lane -> (block b = lane>>3, r = lane&7),
// elements b*64 + r + 8j.
template<bool INV>
__device__ __forceinline__ void mid_M2(float* re, float* im, int lane, int wv) {
    float twr[7], twi[7];
    const float sgn = INV ? 1.0f : -1.0f;
    fill_pyr<2>(sgn * (TWO_PI / 64.0f) * (float)(lane & 7), CP4, sgn * SP4, twr, twi);
    const int sub = ((lane >> 3) << 6) + (lane & 7);
    #pragma unroll
    for (int r = 0; r < 2; ++r) {
        const int base = (((wv << 1) | r) << 9) + sub;
        float ar[8], ai[8];
        #pragma unroll
        for (int j = 0; j < 8; ++j) {
            const int p = SW(base + (j << 3));
            ar[j] = re[p]; ai[j] = im[p];
        }
        if (INV) dit_apply<3>(ar, ai, twr, twi);
        else     dif_apply<3>(ar, ai, twr, twi);
        #pragma unroll
        for (int j = 0; j < 8; ++j) {
            const int p = SW(base + (j << 3));
            re[p] = ar[j]; im[p] = ai[j];
        }
    }
}

__global__ __launch_bounds__(NT, 4) void kfft_kernel(const float* __restrict__ K,
                                                     const float* __restrict__ D,
                                                     float2* __restrict__ Kf) {
    __shared__ float re[LL];
    __shared__ float im[LL];
    const int h = blockIdx.x;
    const int tid = threadIdx.x;
    const float* Kr = K + (size_t)h * LL;
    float xr[16], xi[16];
    #pragma unroll
    for (int m = 0; m < 16; ++m) {
        xr[m] = Kr[tid + (m << 9)];
        xi[m] = 0.0f;
    }
    fwd_A(xr, xi, tid, re, im);
    __syncthreads();

    const int lane = tid & 63, wv = tid >> 6;
    mid_M1<false>(re, im, lane, wv);
    mid_M2<false>(re, im, lane, wv);

    // M3 fwd (spans 4/2/1, constant pyramid -> folded) + fold kw = (X + D[h])/N;
    // per-lane contiguous 8 float2 = 4x dwordx4 stores, natural element order.
    {
        const float dh = D[h];
        const float invN = 1.0f / (float)LL;
        float twd_r[7], twd_i[7];
        fill_pyr_cs<2>(1.0f, 0.0f, CP4, -SP4, twd_r, twd_i);
        #pragma unroll
        for (int r = 0; r < 2; ++r) {
            const int eb = (((wv << 1) | r) << 9) + (lane << 3);
            float yr[8], yi[8];
            #pragma unroll
            for (int j = 0; j < 8; ++j) {
                const int p = SW(eb + j);
                yr[j] = re[p]; yi[j] = im[p];
            }
            dif_apply<3>(yr, yi, twd_r, twd_i);
            float4* o4 = (float4*)(Kf + (size_t)h * LL + eb);
            #pragma unroll
            for (int jj = 0; jj < 4; ++jj) {
                float4 v;
                v.x = (yr[2 * jj]     + dh) * invN; v.y = yi[2 * jj]     * invN;
                v.z = (yr[2 * jj + 1] + dh) * invN; v.w = yi[2 * jj + 1] * invN;
                o4[jj] = v;
            }
        }
    }
}

__global__ __launch_bounds__(NT, 4) void conv_kernel(const float* __restrict__ u,
                                                     const float2* __restrict__ Kf,
                                                     float* __restrict__ out) {
    __shared__ float re[LL];
    __shared__ float im[LL];
    const int tid = threadIdx.x;
    const int h = blockIdx.x & (HH - 1);
    const int pr_ = blockIdx.x >> 8;        // batch pair 0..3
    const size_t off0 = ((size_t)(pr_ * 2) * HH + h) * LL;
    const size_t off1 = off0 + (size_t)HH * LL;
    const float* u0 = u + off0;
    const float* u1 = u + off1;

    float xr[16], xi[16];
    #pragma unroll
    for (int m = 0; m < 16; ++m) {
        xr[m] = u0[tid + (m << 9)];
        xi[m] = u1[tid + (m << 9)];
    }
    fwd_A(xr, xi, tid, re, im);       // z = u0 + i*u1
    __syncthreads();

    const int lane = tid & 63, wv = tid >> 6;
    const float2* kf = Kf + (size_t)h * LL;

    // kw prefetch for both chunks (4x dwordx4 each, per-lane contiguous 64B),
    // consumed two LDS passes later (latency hidden under M1+M2).
    float kwr[2][8], kwi[2][8];
    #pragma unroll
    for (int r = 0; r < 2; ++r) {
        const int eb = (((wv << 1) | r) << 9) + (lane << 3);
        const float4* kp = (const float4*)(kf + eb);
        #pragma unroll
        for (int jj = 0; jj < 4; ++jj) {
            const float4 v = kp[jj];
            kwr[r][2 * jj] = v.x;     kwi[r][2 * jj] = v.y;
            kwr[r][2 * jj + 1] = v.z; kwi[r][2 * jj + 1] = v.w;
        }
    }

    // ---- wave-private middle: no __syncthreads until pass A' ----
    mid_M1<false>(re, im, lane, wv);
    mid_M2<false>(re, im, lane, wv);

    // Merged M3: spans 4/2/1 fwd, *kw, inverse 1/2/4. Constant pyramids (folded).
    {
        float twd_r[7], twd_i[7], twu_r[7], twu_i[7];
        fill_pyr_cs<2>(1.0f, 0.0f, CP4, -SP4, twd_r, twd_i);
        fill_pyr_cs<2>(1.0f, 0.0f, CP4, SP4, twu_r, twu_i);
        #pragma unroll
        for (int r = 0; r < 2; ++r) {
            const int eb = (((wv << 1) | r) << 9) + (lane << 3);
            float yr[8], yi[8];
            #pragma unroll
            for (int j = 0; j < 8; ++j) {
                const int p = SW(eb + j);
                yr[j] = re[p]; yi[j] = im[p];
            }
            dif_apply<3>(yr, yi, twd_r, twd_i);
            #pragma unroll
            for (int j = 0; j < 8; ++j) {
                const float a = yr[j], b = yi[j];
                yr[j] = a * kwr[r][j] - b * kwi[r][j];
                yi[j] = a * kwi[r][j] + b * kwr[r][j];
            }
            dit_apply<3>(yr, yi, twu_r, twu_i);
            #pragma unroll
            for (int j = 0; j < 8; ++j) {
                const int p = SW(eb + j);
                re[p] = yr[j]; im[p] = yi[j];
            }
        }
    }

    mid_M2<true>(re, im, lane, wv);
    mid_M1<true>(re, im, lane, wv);
    __syncthreads();

    // Inv pass A' (spans 512..4096) + epilogue (skip/norm folded into kw).
    {
        float twr[15], twi[15];
        #pragma unroll
        for (int m = 0; m < 16; ++m) {
            const int p = SW(tid + (m << 9));
            xr[m] = re[p]; xi[m] = im[p];
        }
        fill_pyr<3>((TWO_PI / 8192.0f) * (float)tid, CP8, SP8, twr, twi);
        dit_apply<4>(xr, xi, twr, twi);
    }
    float* o0 = out + off0;
    float* o1 = out + off1;
    #pragma unroll
    for (int m = 0; m < 16; ++m) {
        const int n = tid + (m << 9);
        o0[n] = fast_tanh(xr[m]);
        o1[n] = fast_tanh(xi[m]);
    }
}

extern "C" void kernel_launch(void* const* d_in, const int* in_sizes, int n_in,
                              void* d_out, int out_size, void* d_ws, size_t ws_size,
                              hipStream_t stream) {
    const float* u = (const float*)d_in[0];   // (8, 256, 8192)
    const float* K = (const float*)d_in[1];   // (256, 8192)
    const float* D = (const float*)d_in[2];   // (256,)
    float* out = (float*)d_out;               // (8, 256, 8192)
    float2* Kf = (float2*)d_ws;               // 256 * 8192 float2 = 16 MB

    kfft_kernel<<<dim3(HH), dim3(NT), 0, stream>>>(K, D, Kf);
    conv_kernel<<<dim3(4 * HH), dim3(NT), 0, stream>>>(u, Kf, out);
}